// Round 10
// baseline (111.783 us; speedup 1.0000x reference)
//
#include <hip/hip_runtime.h>
#include <hip/hip_fp8.h>

typedef float f32x4 __attribute__((ext_vector_type(4)));

#define N_TOTAL 262144
#define D 128
#define K_TOTAL 1024
#define BN 128
#define NBLK (N_TOTAL / BN)  // 2048
#define BIGF 256.0f
#define TILEB 8192  // 64 centroids x 128 dims x 1 B (fp8)

__device__ __forceinline__ unsigned f2fp8(float x) {
  return (unsigned)__hip_fp8_e4m3(x).__x;
}

__device__ __forceinline__ unsigned umax(unsigned a, unsigned b) {
  return a > b ? a : b;
}

// Kernel 1: codebook fp32 -> fp8 e4m3 (tile-major row layout) + BIG - 0.5||m||^2.
__global__ void prep_means(const float* __restrict__ means,
                           unsigned char* __restrict__ mbf8,
                           float* __restrict__ bigm2) {
  int k = blockIdx.x, t = threadIdx.x;  // 1024 blocks x 64 threads
  float a = means[k * D + 2 * t];
  float b = means[k * D + 2 * t + 1];
  int ts = k >> 6, j = k & 63;
  unsigned short pk = (unsigned short)(f2fp8(a) | (f2fp8(b) << 8));
  *(unsigned short*)(mbf8 + ts * TILEB + j * 128 + 2 * t) = pk;
  float s = a * a + b * b;
#pragma unroll
  for (int m = 32; m; m >>= 1) s += __shfl_down(s, m, 64);
  if (t == 0) bigm2[k] = BIGF - 0.5f * s;
}

// Kernel 2: 128 rows/block (4 waves x 32 rows), 2048 blocks -> 8 blocks/CU
// available; ~21KB LDS + ~70 VGPR -> 6-7 co-resident. A in regs (fp8);
// B tiles (fp8, 8KB) staged global->REG early -> swizzled ds_write after
// compute (T14). Packed-key argmax; exact fp32 loss for winners.
__global__ __launch_bounds__(256) void kmeans_main(
    const float* __restrict__ X, const unsigned char* __restrict__ mbf8,
    const float* __restrict__ bigm2, const float* __restrict__ means,
    float* __restrict__ partials) {
  __shared__ __attribute__((aligned(16))) char Bs[2][TILEB];  // 16 KB dbuf
  __shared__ float m2s[K_TOTAL];                              // 4 KB
  __shared__ int idxs[BN];
  __shared__ float wsum[4];

  const int t = threadIdx.x;
  const int l = t & 63;
  const int w = t >> 6;
  const int lr = l & 15;
  const int lhi = l >> 4;
  const int rot = blockIdx.x & 15;
  const long nbase = (long)blockIdx.x * BN;

  // ---- A fragments: 32 rows/wave, fp32 -> fp8, 8 bytes (1 reg-pair) each ----
  long a[2][4];  // [row-sub][d-sub]
#pragma unroll
  for (int rs = 0; rs < 2; ++rs)
#pragma unroll
    for (int ds = 0; ds < 4; ++ds) {
      const float* ap =
          X + (nbase + w * 32 + rs * 16 + lr) * D + ds * 32 + lhi * 8;
      float4 v0 = *(const float4*)ap;
      float4 v1 = *(const float4*)(ap + 4);
      unsigned lo = f2fp8(v0.x) | (f2fp8(v0.y) << 8) | (f2fp8(v0.z) << 16) |
                    (f2fp8(v0.w) << 24);
      unsigned hi = f2fp8(v1.x) | (f2fp8(v1.y) << 8) | (f2fp8(v1.z) << 16) |
                    (f2fp8(v1.w) << 24);
      a[rs][ds] = (long)(((unsigned long long)hi << 32) | lo);
    }

  // ---- stage bigm2 into LDS (once, all 16 tiles) ----
  {
    float4 v = ((const float4*)bigm2)[t];  // 256*4 = 1024
    *(float4*)(m2s + t * 4) = v;
  }

  // ---- read-side swizzled fragment offsets ----
  // frag(row, ds) at row*128 + ((ds*4 + lhi) ^ ((row&7)<<1)) * 8 ; row=kt*16+lr
  int roff[4];
#pragma unroll
  for (int ds = 0; ds < 4; ++ds)
    roff[ds] = lr * 128 + ((((ds * 4 + lhi) ^ ((lr & 7) << 1))) << 3);

  // ---- write-side staging map: thread t owns linear bytes [t*32, t*32+32) ----
  const int srow = t >> 2;                              // 0..63
  const int sq0 = (t & 3) * 4;                          // slot base 0..12
  const unsigned sswz = (unsigned)((srow & 7) << 1);
  const unsigned wdst0 = (unsigned)(srow * 128 + (((unsigned)sq0 ^ sswz) << 3));
  const unsigned wdst1 =
      (unsigned)(srow * 128 + ((((unsigned)sq0 + 2u) ^ sswz) << 3));

  unsigned bk[2][4];  // running packed keys per (rs, e)
#pragma unroll
  for (int rs = 0; rs < 2; ++rs)
#pragma unroll
    for (int e = 0; e < 4; ++e) bk[rs][e] = 0u;

  // ---- prologue: stage tile `rot` into Bs[0] ----
  {
    const char* src = (const char*)mbf8 + rot * TILEB;
    uint4 s0 = *(const uint4*)(src + t * 32);
    uint4 s1 = *(const uint4*)(src + t * 32 + 16);
    *(uint4*)(Bs[0] + wdst0) = s0;
    *(uint4*)(Bs[0] + wdst1) = s1;
  }
  __syncthreads();

#define COMPUTE_TILE(TID, BP)                                                  \
  {                                                                            \
    _Pragma("unroll") for (int kt_ = 0; kt_ < 4; ++kt_) {                      \
      float m2v_ = m2s[(TID) * 64 + kt_ * 16 + lr];                            \
      f32x4 ci_ = {m2v_, m2v_, m2v_, m2v_};                                    \
      long b0_ = *(const long*)((BP) + kt_ * 2048 + roff[0]);                  \
      long b1_ = *(const long*)((BP) + kt_ * 2048 + roff[1]);                  \
      long b2_ = *(const long*)((BP) + kt_ * 2048 + roff[2]);                  \
      long b3_ = *(const long*)((BP) + kt_ * 2048 + roff[3]);                  \
      unsigned kk_ = (unsigned)((TID) * 64 + kt_ * 16) | (unsigned)lr;         \
      _Pragma("unroll") for (int rs_ = 0; rs_ < 2; ++rs_) {                    \
        f32x4 acc_ = __builtin_amdgcn_mfma_f32_16x16x32_fp8_fp8(               \
            a[rs_][0], b0_, ci_, 0, 0, 0);                                     \
        acc_ = __builtin_amdgcn_mfma_f32_16x16x32_fp8_fp8(a[rs_][1], b1_,      \
                                                          acc_, 0, 0, 0);      \
        acc_ = __builtin_amdgcn_mfma_f32_16x16x32_fp8_fp8(a[rs_][2], b2_,      \
                                                          acc_, 0, 0, 0);      \
        acc_ = __builtin_amdgcn_mfma_f32_16x16x32_fp8_fp8(a[rs_][3], b3_,      \
                                                          acc_, 0, 0, 0);      \
        unsigned k0_ = (__float_as_uint(acc_[0]) & 0xFFFFFC00u) | kk_;         \
        unsigned k1_ = (__float_as_uint(acc_[1]) & 0xFFFFFC00u) | kk_;         \
        unsigned k2_ = (__float_as_uint(acc_[2]) & 0xFFFFFC00u) | kk_;         \
        unsigned k3_ = (__float_as_uint(acc_[3]) & 0xFFFFFC00u) | kk_;         \
        bk[rs_][0] = umax(bk[rs_][0], k0_);                                    \
        bk[rs_][1] = umax(bk[rs_][1], k1_);                                    \
        bk[rs_][2] = umax(bk[rs_][2], k2_);                                    \
        bk[rs_][3] = umax(bk[rs_][3], k3_);                                    \
      }                                                                        \
    }                                                                          \
  }

  int cur = 0;
  for (int ks = 0; ks < 16; ++ks) {
    const int tid = (rot + ks) & 15;
    uint4 s0, s1;
    if (ks < 15) {
      // issue next tile's global loads EARLY (latency hides under compute)
      const char* src = (const char*)mbf8 + (((rot + ks + 1) & 15) * TILEB);
      s0 = *(const uint4*)(src + t * 32);
      s1 = *(const uint4*)(src + t * 32 + 16);
    }
    const char* bp = Bs[cur];
    COMPUTE_TILE(tid, bp);
    if (ks < 15) {
      char* dst = Bs[cur ^ 1];
      *(uint4*)(dst + wdst0) = s0;
      *(uint4*)(dst + wdst1) = s1;
    }
    __syncthreads();
    cur ^= 1;
  }
#undef COMPUTE_TILE

  // ---- reduce keys across the 16 column-lanes; extract centroid idx ----
#pragma unroll
  for (int rs = 0; rs < 2; ++rs)
#pragma unroll
    for (int e = 0; e < 4; ++e) {
      unsigned k = bk[rs][e];
#pragma unroll
      for (int m = 1; m < 16; m <<= 1) {
        unsigned o = (unsigned)__shfl_xor((int)k, m, 64);
        k = umax(k, o);
      }
      if (lr == 0) idxs[w * 32 + rs * 16 + lhi * 4 + e] = (int)(k & 1023u);
    }
  __syncthreads();

  // ---- exact fp32 loss for assigned centroids (2 threads per row) ----
  {
    int row = t >> 1, h = t & 1;
    long n = nbase + row;
    int ai = idxs[row];
    const float4* xr = (const float4*)(X + n * D + h * 64);
    const float4* mr = (const float4*)(means + (long)ai * D + h * 64);
    float s = 0.f;
#pragma unroll
    for (int i = 0; i < 16; ++i) {
      float4 xv = xr[i];
      float4 mv = mr[i];
      float d0 = xv.x - mv.x, d1 = xv.y - mv.y;
      float d2 = xv.z - mv.z, d3 = xv.w - mv.w;
      s = fmaf(d0, d0, s);
      s = fmaf(d1, d1, s);
      s = fmaf(d2, d2, s);
      s = fmaf(d3, d3, s);
    }
#pragma unroll
    for (int m = 32; m; m >>= 1) s += __shfl_down(s, m, 64);
    if (l == 0) wsum[w] = s;
  }
  __syncthreads();
  if (t == 0) partials[blockIdx.x] = wsum[0] + wsum[1] + wsum[2] + wsum[3];
}

// Kernel 3: deterministic fixed-order final reduction (double accum).
__global__ void reduce_loss(const float* __restrict__ partials,
                            float* __restrict__ out) {
  __shared__ double ws[4];
  int t = threadIdx.x;
  double s = 0.0;
  for (int i = t; i < NBLK; i += 256) s += (double)partials[i];
#pragma unroll
  for (int m = 32; m; m >>= 1) s += __shfl_down(s, m, 64);
  if ((t & 63) == 0) ws[t >> 6] = s;
  __syncthreads();
  if (t == 0) out[0] = (float)(ws[0] + ws[1] + ws[2] + ws[3]);
}

extern "C" void kernel_launch(void* const* d_in, const int* in_sizes, int n_in,
                              void* d_out, int out_size, void* d_ws,
                              size_t ws_size, hipStream_t stream) {
  const float* X = (const float*)d_in[0];
  const float* means = (const float*)d_in[1];
  float* out = (float*)d_out;
  char* ws = (char*)d_ws;
  unsigned char* mbf8 = (unsigned char*)ws;         // 131072 B
  float* bigm2 = (float*)(ws + 131072);             // 4096 B
  float* partials = (float*)(ws + 131072 + 4096);   // 8192 B

  prep_means<<<K_TOTAL, 64, 0, stream>>>(means, mbf8, bigm2);
  kmeans_main<<<NBLK, 256, 0, stream>>>(X, mbf8, bigm2, means, partials);
  reduce_loss<<<1, 256, 0, stream>>>(partials, out);
}

// Round 11
// 101.963 us; speedup vs baseline: 1.0963x; 1.0963x over previous
//
#include <hip/hip_runtime.h>
#include <hip/hip_fp8.h>

typedef int v8i __attribute__((ext_vector_type(8)));
typedef float f32x16 __attribute__((ext_vector_type(16)));

#define N_TOTAL 262144
#define D 128
#define K_TOTAL 1024
#define BN 128
#define NBLK (N_TOTAL / BN)  // 2048
#define BIGF 256.0f
#define TILEB 8192  // 64 centroids x 128 dims x 1 B (fp8), operand-order
#define NT 16

__device__ __forceinline__ unsigned f2fp8(float x) {
  return (unsigned)__hip_fp8_e4m3(x).__x;
}
__device__ __forceinline__ unsigned umx(unsigned a, unsigned b) {
  return a > b ? a : b;
}

// Kernel 1: codebook fp32 -> fp8 e4m3 packed in EXACT mfma-operand order:
// within tile ts (64 centroids), col-group cg (32 centroids):
//   byte for (centroid c = cg*32+cl, dim d = kc*64 + g*32 + rem) lives at
//   cg*4096 + kc*2048 + (rem>>4)*1024 + (g*32+cl)*16 + (rem&15)
// so MFMA lane l = g*32+cl reads its 16B at linear offset l*16. Also emits
// bigm2[k] = BIG - 0.5*||m||^2.
__global__ void prep_means(const float* __restrict__ means,
                           unsigned char* __restrict__ mbf8,
                           float* __restrict__ bigm2) {
  int k = blockIdx.x, t = threadIdx.x;  // 1024 blocks x 64 threads
  int ts = k >> 6, c = k & 63;
  int cg = c >> 5, cl = c & 31;
  unsigned char* tb = mbf8 + ts * TILEB + cg * 4096;
  float v0 = means[k * D + 2 * t];
  float v1 = means[k * D + 2 * t + 1];
#pragma unroll
  for (int i = 0; i < 2; ++i) {
    int d = 2 * t + i;
    int kc = d >> 6, dr = d & 63, g = dr >> 5, rem = dr & 31;
    tb[kc * 2048 + (rem >> 4) * 1024 + (g * 32 + cl) * 16 + (rem & 15)] =
        (unsigned char)f2fp8(i ? v1 : v0);
  }
  float s = v0 * v0 + v1 * v1;
#pragma unroll
  for (int m = 32; m; m >>= 1) s += __shfl_down(s, m, 64);
  if (t == 0) bigm2[k] = BIGF - 0.5f * s;
}

union BOp {
  uint4 q[2];
  v8i v;
};

// Kernel 2: 128 rows/block, 4 waves x 32 rows (one 32x32 MFMA row-tile each).
// A in regs (fp8, 16 VGPR). B tiles streamed via T14 reg-staging into a
// double-buffered LDS copy that is a LINEAR byte image (operand-order) ->
// zero bank conflicts. 4x mfma_scale_f32_32x32x64_f8f6f4 per tile per wave.
// Packed-key argmax on the 16-reg accumulator; exact fp32 loss for winners.
__global__ __launch_bounds__(256) void kmeans_main(
    const float* __restrict__ X, const unsigned char* __restrict__ mbf8,
    const float* __restrict__ bigm2, const float* __restrict__ means,
    float* __restrict__ partials) {
  __shared__ __attribute__((aligned(16))) char Bs[2][TILEB];  // 16 KB dbuf
  __shared__ float m2s[K_TOTAL];                              // 4 KB
  __shared__ int idxs[BN];
  __shared__ float wsum[4];

  const int t = threadIdx.x;
  const int l = t & 63;
  const int w = t >> 6;
  const int row = l & 31;  // A-row within the wave's 32-row tile
  const int g = l >> 5;    // K-half within a 64-wide K-chunk
  const int rot = blockIdx.x & 15;
  const long nbase = (long)blockIdx.x * BN;

  // ---- A fragments: row (w*32+row), dims kc*64 + g*32 + 0..31 -> 8 dwords ----
  v8i af[2];
  {
    const float* xr = X + (nbase + w * 32 + row) * D + g * 32;
#pragma unroll
    for (int kc = 0; kc < 2; ++kc) {
      v8i av;
#pragma unroll
      for (int j = 0; j < 8; ++j) {
        float4 v = *(const float4*)(xr + kc * 64 + j * 4);
        av[j] = (int)(f2fp8(v.x) | (f2fp8(v.y) << 8) | (f2fp8(v.z) << 16) |
                      (f2fp8(v.w) << 24));
      }
      af[kc] = av;
    }
  }

  // ---- stage bigm2 into LDS (once, all 16 tiles) ----
  {
    float4 v = ((const float4*)bigm2)[t];  // 256*4 = 1024
    *(float4*)(m2s + t * 4) = v;
  }

  unsigned bk[16];  // running packed keys per accumulator reg
#pragma unroll
  for (int e = 0; e < 16; ++e) bk[e] = 0u;

  // ---- prologue: stage tile `rot` (pure linear copy, conflict-free) ----
  {
    const char* src = (const char*)mbf8 + rot * TILEB;
    uint4 s0 = *(const uint4*)(src + t * 16);
    uint4 s1 = *(const uint4*)(src + 4096 + t * 16);
    *(uint4*)(Bs[0] + t * 16) = s0;
    *(uint4*)(Bs[0] + 4096 + t * 16) = s1;
  }
  __syncthreads();

#define COMPUTE_TILE(TID, BP)                                                  \
  {                                                                            \
    _Pragma("unroll") for (int cg_ = 0; cg_ < 2; ++cg_) {                      \
      float m2v_ = m2s[(TID) * 64 + cg_ * 32 + row];                           \
      f32x16 acc_;                                                             \
      _Pragma("unroll") for (int e_ = 0; e_ < 16; ++e_) acc_[e_] = m2v_;       \
      const char* bb_ = (BP) + cg_ * 4096;                                     \
      BOp u0_, u1_;                                                            \
      u0_.q[0] = *(const uint4*)(bb_ + l * 16);                                \
      u0_.q[1] = *(const uint4*)(bb_ + 1024 + l * 16);                         \
      u1_.q[0] = *(const uint4*)(bb_ + 2048 + l * 16);                         \
      u1_.q[1] = *(const uint4*)(bb_ + 3072 + l * 16);                         \
      acc_ = __builtin_amdgcn_mfma_scale_f32_32x32x64_f8f6f4(                  \
          af[0], u0_.v, acc_, 0, 0, 0, 127, 0, 127);                           \
      acc_ = __builtin_amdgcn_mfma_scale_f32_32x32x64_f8f6f4(                  \
          af[1], u1_.v, acc_, 0, 0, 0, 127, 0, 127);                           \
      unsigned ci_ = (unsigned)((TID) * 64 + cg_ * 32 + row);                  \
      _Pragma("unroll") for (int e_ = 0; e_ < 16; ++e_) {                      \
        unsigned key_ = (__float_as_uint(acc_[e_]) & 0xFFFFFC00u) | ci_;       \
        bk[e_] = umx(bk[e_], key_);                                            \
      }                                                                        \
    }                                                                          \
  }

  int cur = 0;
  for (int ks = 0; ks < NT; ++ks) {
    const int tid = (rot + ks) & 15;
    uint4 s0, s1;
    if (ks < NT - 1) {
      // issue next tile's global loads EARLY (latency hides under compute)
      const char* src = (const char*)mbf8 + (((rot + ks + 1) & 15) * TILEB);
      s0 = *(const uint4*)(src + t * 16);
      s1 = *(const uint4*)(src + 4096 + t * 16);
    }
    const char* bp = Bs[cur];
    COMPUTE_TILE(tid, bp);
    if (ks < NT - 1) {
      char* dst = Bs[cur ^ 1];
      *(uint4*)(dst + t * 16) = s0;
      *(uint4*)(dst + 4096 + t * 16) = s1;
    }
    __syncthreads();
    cur ^= 1;
  }
#undef COMPUTE_TILE

  // ---- reduce keys across the 32 column-lanes of each half; extract idx ----
  // D row for (reg e, half g): row = (e&3) + 8*(e>>2) + 4*g  [m74/m101]
#pragma unroll
  for (int e = 0; e < 16; ++e) {
    unsigned k = bk[e];
#pragma unroll
    for (int m = 1; m < 32; m <<= 1) {
      unsigned o = (unsigned)__shfl_xor((int)k, m, 64);
      k = umx(k, o);
    }
    if (row == 0) {
      int rowc = (e & 3) + 8 * (e >> 2) + 4 * g;
      idxs[w * 32 + rowc] = (int)(k & 1023u);
    }
  }
  __syncthreads();

  // ---- exact fp32 loss for assigned centroids (2 threads per row) ----
  {
    int r2 = t >> 1, h = t & 1;
    long n = nbase + r2;
    int ai = idxs[r2];
    const float4* xr = (const float4*)(X + n * D + h * 64);
    const float4* mr = (const float4*)(means + (long)ai * D + h * 64);
    float s = 0.f;
#pragma unroll
    for (int i = 0; i < 16; ++i) {
      float4 xv = xr[i];
      float4 mv = mr[i];
      float d0 = xv.x - mv.x, d1 = xv.y - mv.y;
      float d2 = xv.z - mv.z, d3 = xv.w - mv.w;
      s = fmaf(d0, d0, s);
      s = fmaf(d1, d1, s);
      s = fmaf(d2, d2, s);
      s = fmaf(d3, d3, s);
    }
#pragma unroll
    for (int m = 32; m; m >>= 1) s += __shfl_down(s, m, 64);
    if (l == 0) wsum[w] = s;
  }
  __syncthreads();
  if (t == 0) partials[blockIdx.x] = wsum[0] + wsum[1] + wsum[2] + wsum[3];
}

// Kernel 3: deterministic fixed-order final reduction (double accum).
__global__ void reduce_loss(const float* __restrict__ partials,
                            float* __restrict__ out) {
  __shared__ double ws[4];
  int t = threadIdx.x;
  double s = 0.0;
  for (int i = t; i < NBLK; i += 256) s += (double)partials[i];
#pragma unroll
  for (int m = 32; m; m >>= 1) s += __shfl_down(s, m, 64);
  if ((t & 63) == 0) ws[t >> 6] = s;
  __syncthreads();
  if (t == 0) out[0] = (float)(ws[0] + ws[1] + ws[2] + ws[3]);
}

extern "C" void kernel_launch(void* const* d_in, const int* in_sizes, int n_in,
                              void* d_out, int out_size, void* d_ws,
                              size_t ws_size, hipStream_t stream) {
  const float* X = (const float*)d_in[0];
  const float* means = (const float*)d_in[1];
  float* out = (float*)d_out;
  char* ws = (char*)d_ws;
  unsigned char* mbf8 = (unsigned char*)ws;         // 131072 B
  float* bigm2 = (float*)(ws + 131072);             // 4096 B
  float* partials = (float*)(ws + 131072 + 4096);   // 8192 B

  prep_means<<<K_TOTAL, 64, 0, stream>>>(means, mbf8, bigm2);
  kmeans_main<<<NBLK, 256, 0, stream>>>(X, mbf8, bigm2, means, partials);
  reduce_loss<<<1, 256, 0, stream>>>(partials, out);
}